// Round 4
// baseline (443.905 us; speedup 1.0000x reference)
//
#include <hip/hip_runtime.h>
#include <hip/hip_bf16.h>
#include <stdint.h>

#define N_NODES 100000
#define DIM 128
#define NREL 4
#define NEDGE 500000
#define M_FLAT (NREL * N_NODES)        // 400000 flat (r,node) slots
#define TOT_E (NREL * NEDGE)           // 2M edges
#define NBK ((M_FLAT + 2047) / 2048)   // 196 buckets of 2048 flat slots
#define CHUNK 4096                     // edges per bscatter block
#define LDA 136                        // 128 + 8 bf16 pad

typedef __attribute__((ext_vector_type(8))) short short8;
typedef __attribute__((ext_vector_type(4))) float f32x4;

__device__ __forceinline__ unsigned short f2bf(float f) {
  unsigned int u = __float_as_uint(f);
  u += 0x7fffu + ((u >> 16) & 1u);   // RNE
  return (unsigned short)(u >> 16);
}
__device__ __forceinline__ float bflo(unsigned int v) { return __uint_as_float((v & 0xffffu) << 16); }
__device__ __forceinline__ float bfhi(unsigned int v) { return __uint_as_float(v & 0xffff0000u); }

// Combined B in MFMA fragment order. b=0: (sum_r Wself_r)/4 ; b=1+r: Wneigh_r/4.
__global__ void prep_kernel(const float* __restrict__ Ws, const float* __restrict__ Wn,
                            const float* __restrict__ bv, unsigned short* __restrict__ Wt,
                            float* __restrict__ biasc) {
  int tid = blockIdx.x * 256 + threadIdx.x;
  if (tid < 5 * DIM * DIM) {
    int b = tid / (DIM * DIM);
    int idx = tid - b * DIM * DIM;   // k*DIM + n
    int k = idx >> 7, n = idx & 127;
    float v;
    if (b == 0)
      v = 0.25f * (Ws[idx] + Ws[DIM * DIM + idx] + Ws[2 * DIM * DIM + idx] + Ws[3 * DIM * DIM + idx]);
    else
      v = 0.25f * Wn[(b - 1) * DIM * DIM + idx];
    int ks = k >> 5, kq = (k >> 3) & 3, j = k & 7;
    int ct = n >> 4, lr = n & 15;
    int lane = kq * 16 + lr;
    Wt[((((b * 4 + ks) * 8) + ct) * 64 + lane) * 8 + j] = f2bf(v);
  }
  if (tid < DIM)
    biasc[tid] = 0.25f * (bv[tid] + bv[DIM + tid] + bv[2 * DIM + tid] + bv[3 * DIM + tid]);
}

__global__ void xb_kernel(const float* __restrict__ x, unsigned short* __restrict__ xb) {
  int i = blockIdx.x * 256 + threadIdx.x;
  if (i < N_NODES * DIM / 4) {
    float4 v = ((const float4*)x)[i];
    ushort4 s;
    s.x = f2bf(v.x); s.y = f2bf(v.y); s.z = f2bf(v.z); s.w = f2bf(v.w);
    ((ushort4*)xb)[i] = s;
  }
}

// Bucket histogram: LDS-reduced, 196 global atomics per block.
__global__ __launch_bounds__(256) void bhist_kernel(const int* __restrict__ dst,
                                                    int* __restrict__ bcnt) {
  __shared__ int h[NBK];
  int tid = threadIdx.x;
  for (int i = tid; i < NBK; i += 256) h[i] = 0;
  __syncthreads();
  int base = blockIdx.x * 2048;
#pragma unroll
  for (int k = 0; k < 8; ++k) {
    int idx = base + k * 256 + tid;
    if (idx < TOT_E) {
      int r = idx / NEDGE;
      int fl = r * N_NODES + dst[idx];
      atomicAdd(&h[fl >> 11], 1);
    }
  }
  __syncthreads();
  for (int i = tid; i < NBK; i += 256)
    if (h[i]) atomicAdd(&bcnt[i], h[i]);
}

// Scan 196 bucket counts -> boffs[0..NBK], init bcur, set offs[M_FLAT].
__global__ void bscan_kernel(const int* __restrict__ bcnt, int* __restrict__ boffs,
                             int* __restrict__ bcur, int* __restrict__ offs) {
  __shared__ int sh[256];
  int t = threadIdx.x;
  int v = (t < NBK) ? bcnt[t] : 0;
  sh[t] = v;
  __syncthreads();
  for (int o = 1; o < 256; o <<= 1) {
    int u = (t >= o) ? sh[t - o] : 0;
    __syncthreads();
    sh[t] += u;
    __syncthreads();
  }
  int excl = sh[t] - v;
  if (t < NBK) { boffs[t] = excl; bcur[t] = excl; }
  if (t == 255) { boffs[NBK] = sh[t]; offs[M_FLAT] = sh[t]; }
}

// Local sort of a 4096-edge chunk by bucket; coalesced run-writes of packed pairs.
__global__ __launch_bounds__(256) void bscatter_kernel(
    const int* __restrict__ src, const int* __restrict__ dst,
    int* __restrict__ bcur, unsigned int* __restrict__ gpairs) {
  __shared__ unsigned int buf[CHUNK];
  __shared__ unsigned short barr[CHUNK];
  __shared__ int hist[NBK];
  __shared__ int sbase[NBK];
  __shared__ int lcur[NBK];
  __shared__ int gbase[NBK];
  __shared__ int part[256];
  int tid = threadIdx.x;
  int base = blockIdx.x * CHUNK;
  int m = TOT_E - base; if (m > CHUNK) m = CHUNK;
  for (int i = tid; i < NBK; i += 256) { hist[i] = 0; lcur[i] = 0; }
  __syncthreads();
  unsigned int pk[CHUNK / 256];
  int bk[CHUNK / 256];
#pragma unroll
  for (int k = 0; k < CHUNK / 256; ++k) {
    int i = k * 256 + tid;
    int idx = base + i;
    int b = -1; unsigned int p = 0;
    if (i < m) {
      int r = idx / NEDGE;
      int fl = r * N_NODES + dst[idx];
      b = fl >> 11;
      p = ((unsigned int)(fl & 2047) << 17) | (unsigned int)src[idx];
      atomicAdd(&hist[b], 1);
    }
    pk[k] = p; bk[k] = b;
  }
  __syncthreads();
  {
    int v = (tid < NBK) ? hist[tid] : 0;
    part[tid] = v;
    __syncthreads();
    for (int o = 1; o < 256; o <<= 1) {
      int u = (tid >= o) ? part[tid - o] : 0;
      __syncthreads();
      part[tid] += u;
      __syncthreads();
    }
    if (tid < NBK) sbase[tid] = part[tid] - v;
  }
  __syncthreads();
#pragma unroll
  for (int k = 0; k < CHUNK / 256; ++k) {
    if (bk[k] >= 0) {
      int pos = sbase[bk[k]] + atomicAdd(&lcur[bk[k]], 1);
      buf[pos] = pk[k];
      barr[pos] = (unsigned short)bk[k];
    }
  }
  __syncthreads();
  if (tid < NBK && hist[tid] > 0)
    gbase[tid] = atomicAdd(&bcur[tid], hist[tid]) - sbase[tid];
  __syncthreads();
  for (int j = tid; j < m; j += 256)
    gpairs[gbase[barr[j]] + j] = buf[j];
}

// One block per bucket: LDS count + scan -> exact CSR (offs, ssrc).
__global__ __launch_bounds__(256) void bfill_kernel(
    const unsigned int* __restrict__ gpairs, const int* __restrict__ boffs,
    int* __restrict__ offs, int* __restrict__ ssrc) {
  __shared__ int lcnt[2048];
  __shared__ int lofs[2048];
  __shared__ int lcur[2048];
  __shared__ int part[256];
  int b = blockIdx.x;
  int tid = threadIdx.x;
  int base = boffs[b];
  int cntb = boffs[b + 1] - base;
  int flBase = b << 11;
  int flCount = M_FLAT - flBase; if (flCount > 2048) flCount = 2048;
  for (int i = tid; i < 2048; i += 256) { lcnt[i] = 0; lcur[i] = 0; }
  __syncthreads();
  for (int j = tid; j < cntb; j += 256)
    atomicAdd(&lcnt[gpairs[base + j] >> 17], 1);
  __syncthreads();
  int vals[8]; int s0 = 0;
#pragma unroll
  for (int k = 0; k < 8; ++k) { vals[k] = lcnt[tid * 8 + k]; s0 += vals[k]; }
  part[tid] = s0;
  __syncthreads();
  for (int o = 1; o < 256; o <<= 1) {
    int u = (tid >= o) ? part[tid - o] : 0;
    __syncthreads();
    part[tid] += u;
    __syncthreads();
  }
  int excl = part[tid] - s0;
#pragma unroll
  for (int k = 0; k < 8; ++k) { lofs[tid * 8 + k] = excl; excl += vals[k]; }
  __syncthreads();
  for (int i = tid; i < flCount; i += 256)
    offs[flBase + i] = base + lofs[i];
  for (int j = tid; j < cntb; j += 256) {
    unsigned int p = gpairs[base + j];
    int li = p >> 17;
    int pos = atomicAdd(&lcur[li], 1);
    ssrc[base + lofs[li] + pos] = (int)(p & 0x1FFFFu);
  }
}

// Fused aggregate+GEMM, barrier-free: each wave owns a 32-row band of the
// 128-row LDS A-tile. Slab 0 stages xb rows; slabs 1..4 are gather-means
// aggregated in-register and written bf16 to the band, then MFMA'd. No
// __syncthreads anywhere: waves' gather latency overlaps other waves' MFMA.
__global__ __launch_bounds__(256) void fused_kernel(
    const unsigned short* __restrict__ xb, const unsigned short* __restrict__ Wt,
    const float* __restrict__ biasc, float* __restrict__ out,
    const int* __restrict__ ssrc, const int* __restrict__ offs) {
  __shared__ unsigned short As[128][LDA];
  int tid = threadIdx.x;
  int rowBase = blockIdx.x * 128;
  int lane = tid & 63;
  int wv = tid >> 6;
  int quad = lane >> 4;
  int lr = lane & 15;
  const short8* Bp = (const short8*)Wt;
  const unsigned int* xb32 = (const unsigned int*)xb;

  float bias8[8];
#pragma unroll
  for (int ct = 0; ct < 8; ++ct) bias8[ct] = biasc[ct * 16 + lr];

  f32x4 zero = {0.f, 0.f, 0.f, 0.f};
  f32x4 acc[2][8];
#pragma unroll
  for (int rt = 0; rt < 2; ++rt)
#pragma unroll
    for (int ct = 0; ct < 8; ++ct) acc[rt][ct] = zero;

  // ---- slab 0: stage this wave's 32 xb rows (wave-private band) ----
#pragma unroll
  for (int p = 0; p < 8; ++p) {
    int unit = p * 64 + lane;            // 512 units of 8 bf16 per band
    int row = wv * 32 + (unit >> 4);
    int c8 = unit & 15;
    int g = rowBase + row;
    short8 val = {0, 0, 0, 0, 0, 0, 0, 0};
    if (g < N_NODES) val = *(const short8*)(xb + (size_t)g * DIM + c8 * 8);
    *(short8*)&As[row][c8 * 8] = val;
  }
#pragma unroll
  for (int ks = 0; ks < 4; ++ks) {
    int k0 = ks * 32 + quad * 8;
    short8 a0 = *(const short8*)&As[wv * 32 + lr][k0];
    short8 a1 = *(const short8*)&As[wv * 32 + 16 + lr][k0];
#pragma unroll
    for (int ct = 0; ct < 8; ++ct) {
      short8 bf = Bp[((0 * 4 + ks) * 8 + ct) * 64 + lane];
      acc[0][ct] = __builtin_amdgcn_mfma_f32_16x16x32_bf16(a0, bf, acc[0][ct], 0, 0, 0);
      acc[1][ct] = __builtin_amdgcn_mfma_f32_16x16x32_bf16(a1, bf, acc[1][ct], 0, 0, 0);
    }
  }

  int n0 = rowBase + wv * 32;
  for (int r = 0; r < NREL; ++r) {
    // 33 CSR offsets for this wave's band via one lane-load + readlane
    int li = (lane > 32) ? 32 : lane;
    int oidx = r * N_NODES + n0 + li;
    if (oidx > M_FLAT) oidx = M_FLAT;
    int ov = offs[oidx];
    for (int j = 0; j < 32; ++j) {
      int n = n0 + j;
      float aL = 0.f, aH = 0.f;
      int c = 0;
      if (n < N_NODES) {
        int start = __builtin_amdgcn_readlane(ov, j);
        int end = __builtin_amdgcn_readlane(ov, j + 1);
        c = end - start;
        for (int e0 = start; e0 < end; e0 += 8) {
          int take = end - e0; if (take > 8) take = 8;
          int ei = lane & 7; if (ei > take - 1) ei = take - 1;
          int vsv = ssrc[e0 + ei];          // one coalesced 32B lane-load
          unsigned int v[8];
#pragma unroll
          for (int k = 0; k < 8; ++k) {
            int s = __builtin_amdgcn_readlane(vsv, k);   // SGPR -> saddr gather
            v[k] = xb32[(size_t)s * 64 + lane];
          }
#pragma unroll
          for (int k = 0; k < 8; ++k) { aL += bflo(v[k]); aH += bfhi(v[k]); }
          float w = (float)(8 - take);     // exact fixup for clamped duplicates
          aL -= w * bflo(v[7]);
          aH -= w * bfhi(v[7]);
        }
      }
      float inv = 1.0f / (float)(c > 0 ? c : 1);
      unsigned int packed =
          ((unsigned int)f2bf(aH * inv) << 16) | (unsigned int)f2bf(aL * inv);
      *((unsigned int*)&As[wv * 32 + j][0] + lane) = packed;
    }
#pragma unroll
    for (int ks = 0; ks < 4; ++ks) {
      int k0 = ks * 32 + quad * 8;
      short8 a0 = *(const short8*)&As[wv * 32 + lr][k0];
      short8 a1 = *(const short8*)&As[wv * 32 + 16 + lr][k0];
#pragma unroll
      for (int ct = 0; ct < 8; ++ct) {
        short8 bf = Bp[(((1 + r) * 4 + ks) * 8 + ct) * 64 + lane];
        acc[0][ct] = __builtin_amdgcn_mfma_f32_16x16x32_bf16(a0, bf, acc[0][ct], 0, 0, 0);
        acc[1][ct] = __builtin_amdgcn_mfma_f32_16x16x32_bf16(a1, bf, acc[1][ct], 0, 0, 0);
      }
    }
  }

#pragma unroll
  for (int rt = 0; rt < 2; ++rt)
#pragma unroll
    for (int i = 0; i < 4; ++i) {
      int g = rowBase + wv * 32 + rt * 16 + quad * 4 + i;
      if (g < N_NODES) {
#pragma unroll
        for (int ct = 0; ct < 8; ++ct)
          out[(size_t)g * DIM + ct * 16 + lr] = acc[rt][ct][i] + bias8[ct];
      }
    }
}

extern "C" void kernel_launch(void* const* d_in, const int* in_sizes, int n_in,
                              void* d_out, int out_size, void* d_ws, size_t ws_size,
                              hipStream_t stream) {
  const float* x = (const float*)d_in[0];
  const int* src = (const int*)d_in[1];
  const int* dst = (const int*)d_in[2];
  const float* Wself = (const float*)d_in[3];
  const float* Wneigh = (const float*)d_in[4];
  const float* bv = (const float*)d_in[5];
  float* out = (float*)d_out;

  char* ws = (char*)d_ws;
  size_t off = 0;
  int* bcnt = (int*)(ws + off);        off += 1024;
  int* boffs = (int*)(ws + off);       off += 1024;
  int* bcur = (int*)(ws + off);        off += 1024;
  unsigned short* Wt = (unsigned short*)(ws + off);  off += 5 * DIM * DIM * 2;        // 160 KB
  float* biasc = (float*)(ws + off);   off += DIM * 4;
  int* offs = (int*)(ws + off);        off += ((size_t)(M_FLAT + 1) * 4 + 15) & ~15;  // 1.6 MB
  unsigned short* xb = (unsigned short*)(ws + off);  off += (size_t)N_NODES * DIM * 2; // 25.6 MB
  unsigned int* gpairs = (unsigned int*)(ws + off);  off += (size_t)TOT_E * 4;         // 8 MB
  int* ssrc = (int*)(ws + off);        off += (size_t)TOT_E * 4;                       // 8 MB

  hipMemsetAsync(bcnt, 0, 1024, stream);
  xb_kernel<<<(N_NODES * DIM / 4 + 255) / 256, 256, 0, stream>>>(x, xb);
  prep_kernel<<<(5 * DIM * DIM + 255) / 256, 256, 0, stream>>>(Wself, Wneigh, bv, Wt, biasc);
  bhist_kernel<<<(TOT_E + 2047) / 2048, 256, 0, stream>>>(dst, bcnt);
  bscan_kernel<<<1, 256, 0, stream>>>(bcnt, boffs, bcur, offs);
  bscatter_kernel<<<(TOT_E + CHUNK - 1) / CHUNK, 256, 0, stream>>>(src, dst, bcur, gpairs);
  bfill_kernel<<<NBK, 256, 0, stream>>>(gpairs, boffs, offs, ssrc);

  int gGemm = (N_NODES + 127) / 128;  // 782
  fused_kernel<<<gGemm, 256, 0, stream>>>(xb, Wt, biasc, out, ssrc, offs);
}